// Round 5
// baseline (313.645 us; speedup 1.0000x reference)
//
#include <hip/hip_runtime.h>

#define HID 2048
#define FIVEH 10240
#define INP 128
#define BATCH 2048

// ---------------- exact f32 GEMM (verified): up[b-row0][n] = input[b]·W[n] + bias[n] --
__global__ __launch_bounds__(256) void gemm32(const float* __restrict__ A,
                                              const float* __restrict__ W,
                                              const float* __restrict__ bias,
                                              float* __restrict__ up,
                                              int row0, int nrows) {
  __shared__ float As[32][128];
  int tid = threadIdx.x;
  int col = blockIdx.x * 256 + tid;
  int rb = blockIdx.y * 32;
  if (rb >= nrows) return;

  for (int v = tid; v < 32 * 32; v += 256) {
    int r = v >> 5, q = v & 31;
    ((float4*)&As[r][0])[q] = ((const float4*)(A + (size_t)(row0 + rb + r) * INP))[q];
  }
  __syncthreads();

  float bv = bias[col];
  float acc[32];
#pragma unroll
  for (int r = 0; r < 32; ++r) acc[r] = bv;

  const float4* wrow = (const float4*)(W + (size_t)col * INP);
#pragma unroll
  for (int kb = 0; kb < 8; ++kb) {
    float4 w0 = wrow[kb * 4 + 0], w1 = wrow[kb * 4 + 1],
           w2 = wrow[kb * 4 + 2], w3 = wrow[kb * 4 + 3];
#pragma unroll
    for (int r = 0; r < 32; ++r) {
      const float4* a4 = (const float4*)&As[r][kb * 16];
      float4 a0 = a4[0], a1 = a4[1], a2 = a4[2], a3 = a4[3];
      acc[r] += a0.x*w0.x + a0.y*w0.y + a0.z*w0.z + a0.w*w0.w
              + a1.x*w1.x + a1.y*w1.y + a1.z*w1.z + a1.w*w1.w
              + a2.x*w2.x + a2.y*w2.y + a2.z*w2.z + a2.w*w2.w
              + a3.x*w3.x + a3.y*w3.y + a3.z*w3.z + a3.w*w3.w;
    }
  }
#pragma unroll
  for (int r = 0; r < 32; ++r)
    up[(size_t)(rb + r) * FIVEH + col] = acc[r];
}

// ---------------- row pipeline (no exotic intrinsics) ----------------
__device__ __forceinline__ void fft_passes(float*& ar, float*& ai, float*& br, float*& bi,
                                           const float* twr, const float* twi,
                                           int tid, float sgn) {
  for (int p = 1; p < HID; p <<= 1) {
#pragma unroll
    for (int t = 0; t < 4; ++t) {
      int i = tid + (t << 8);
      int kk = i & (p - 1);
      int j = ((i - kk) << 1) + kk;
      float xr = ar[i], xi = ai[i];
      float yr = ar[i + 1024], yi = ai[i + 1024];
      float wr = twr[p + kk];
      float wi = sgn * twi[p + kk];   // table = exp(-i*pi*k/p); sgn=-1 conjugates (ifft)
      float tr = wr * yr - wi * yi;
      float ti = wr * yi + wi * yr;
      br[j] = xr + tr;
      bi[j] = xi + ti;
      br[j + p] = xr - tr;
      bi[j + p] = xi - ti;
    }
    __syncthreads();
    float* tmp;
    tmp = ar; ar = br; br = tmp;
    tmp = ai; ai = bi; bi = tmp;
  }
}

// pure-LDS tree reduction over the 256-thread block (no shuffles)
__device__ __forceinline__ void block_reduce2(float& pr, float& pi,
                                              float* redr, float* redi, int tid) {
  redr[tid] = pr; redi[tid] = pi;
  __syncthreads();
  for (int s = 128; s > 0; s >>= 1) {
    if (tid < s) { redr[tid] += redr[tid + s]; redi[tid] += redi[tid + s]; }
    __syncthreads();
  }
  pr = redr[0]; pi = redi[0];
  __syncthreads();  // protect redr/redi for reuse
}

__device__ __forceinline__ void init_twiddles(float* twr, float* twi, int tid) {
  for (int i = tid; i < HID; i += 256) {
    if (i > 0) {
      int p = 1 << (31 - __clz(i));
      int k = i - p;
      float ang = -3.14159265358979f * (float)k / (float)p;
      twr[i] = cosf(ang); twi[i] = sinf(ang);
    } else { twr[0] = 1.f; twi[0] = 0.f; }
  }
}

// omode: 0 = interleaved (re,im) pairs; 1 = planar (re-plane then im-plane); 2 = real only
// UP(e,s) must yield up[b][s*HID + tid + e*256] as float
#define ROW_PIPELINE(UP)                                                        \
  float *car = s0r, *cai = s0i, *cbr = s1r, *cbi = s1i;                         \
  fft_passes(car, cai, cbr, cbi, twr, twi, tid, 1.0f);                          \
  {                                                                             \
    float pr = 0.f, pi = 0.f;                                                   \
    _Pragma("unroll") for (int e = 0; e < 8; ++e) {                             \
      int k = tid + (e << 8);                                                   \
      float u = UP(e, 3); float sv = sinf(u), cv = cosf(u);                     \
      float hr = car[k], hi = cai[k];                                           \
      pr += cv * hr + sv * hi;                                                  \
      pi += cv * hi - sv * hr;                                                  \
    }                                                                           \
    block_reduce2(pr, pi, redr, redi, tid);                                     \
    _Pragma("unroll") for (int e = 0; e < 8; ++e) {                             \
      int k = tid + (e << 8);                                                   \
      float u = UP(e, 3); float sv = sinf(u), cv = cosf(u);                     \
      car[k] -= 2.f * (cv * pr - sv * pi);                                      \
      cai[k] -= 2.f * (cv * pi + sv * pr);                                      \
    }                                                                           \
  }                                                                             \
  __syncthreads();                                                              \
  _Pragma("unroll") for (int e = 0; e < 8; ++e) {                               \
    int k = tid + (e << 8);                                                     \
    float u = UP(e, 1); float sv = sinf(u), cv = cosf(u);                       \
    int pk = perm[k];                                                           \
    float hr = car[pk], hi = cai[pk];                                           \
    cbr[k] = cv * hr - sv * hi;                                                 \
    cbi[k] = cv * hi + sv * hr;                                                 \
  }                                                                             \
  __syncthreads();                                                              \
  { float* t = car; car = cbr; cbr = t; t = cai; cai = cbi; cbi = t; }          \
  fft_passes(car, cai, cbr, cbi, twr, twi, tid, -1.0f);                         \
  float prj_r, prj_i;                                                           \
  {                                                                             \
    float pr = 0.f, pi = 0.f;                                                   \
    _Pragma("unroll") for (int e = 0; e < 8; ++e) {                             \
      int k = tid + (e << 8);                                                   \
      float u = UP(e, 4); float sv = sinf(u), cv = cosf(u);                     \
      float hr = car[k], hi = cai[k];                                           \
      pr += cv * hr + sv * hi;                                                  \
      pi += cv * hi - sv * hr;                                                  \
    }                                                                           \
    block_reduce2(pr, pi, redr, redi, tid);                                     \
    prj_r = pr; prj_i = pi;                                                     \
  }                                                                             \
  const float invN = 1.0f / (float)HID;                                         \
  _Pragma("unroll") for (int e = 0; e < 8; ++e) {                               \
    int k = tid + (e << 8);                                                     \
    float u4 = UP(e, 4); float sv = sinf(u4), cv = cosf(u4);                    \
    float hr = car[k] - 2.f * (cv * prj_r - sv * prj_i);                        \
    float hi = cai[k] - 2.f * (cv * prj_i + sv * prj_r);                        \
    float u2 = UP(e, 2); float s3 = sinf(u2), c3 = cosf(u2);                    \
    float zr = (c3 * hr - s3 * hi) * invN;                                      \
    float zi = (c3 * hi + s3 * hr) * invN;                                      \
    float mag = sqrtf(zr * zr + zi * zi);                                       \
    float nm = mag + beta[k];                                                   \
    nm = nm > 0.f ? nm : 0.f;                                                   \
    float orr, oii;                                                             \
    if (mag > 0.f) { float sc = nm / mag; orr = zr * sc; oii = zi * sc; }       \
    else { orr = nm; oii = 0.f; }                                               \
    long m = (long)b * HID + k;                                                 \
    if (omode == 0) {                                                           \
      if (2 * m + 1 < out_size_l) {                                             \
        float2 o; o.x = orr; o.y = oii;                                         \
        *(float2*)(out + 2 * m) = o;                                            \
      }                                                                         \
    } else if (omode == 1) {                                                    \
      const long half = (long)BATCH * HID;                                      \
      if (half + m < out_size_l) { out[m] = orr; out[half + m] = oii; }         \
    } else {                                                                    \
      if (m < out_size_l) out[m] = orr;                                         \
    }                                                                           \
  }

// ---------------- chunked-path row kernel: reads staged f32 up ----------------
__global__ __launch_bounds__(256) void urnn_row(const float* __restrict__ up,
                                                const float* __restrict__ hxr,
                                                const float* __restrict__ hxi,
                                                const float* __restrict__ beta,
                                                const int* __restrict__ perm,
                                                float* __restrict__ out,
                                                int row0, long out_size_l, int omode) {
  __shared__ float s0r[HID], s0i[HID], s1r[HID], s1i[HID];
  __shared__ float twr[HID], twi[HID];
  __shared__ float redr[256], redi[256];

  int tid = threadIdx.x;
  int b = row0 + blockIdx.x;
  const float* uprow = up + (size_t)blockIdx.x * FIVEH;
#define UPG(e, s) (uprow[(s) * HID + tid + ((e) << 8)])

  init_twiddles(twr, twi, tid);
#pragma unroll
  for (int e = 0; e < 8; ++e) {
    int k = tid + (e << 8);
    float u = UPG(e, 0);
    float sv = sinf(u), cv = cosf(u);
    float hr = hxr[(size_t)b * HID + k];
    float hi = hxi[(size_t)b * HID + k];
    s0r[k] = cv * hr - sv * hi;
    s0i[k] = cv * hi + sv * hr;
  }
  __syncthreads();
  ROW_PIPELINE(UPG)
#undef UPG
}

// ---------------- ws-free fused fallback: per-thread register GEMM (f32 exact) --------
__global__ __launch_bounds__(256) void urnn_fused(const float* __restrict__ A,
                                                  const float* __restrict__ W,
                                                  const float* __restrict__ bias,
                                                  const float* __restrict__ hxr,
                                                  const float* __restrict__ hxi,
                                                  const float* __restrict__ beta,
                                                  const int* __restrict__ perm,
                                                  float* __restrict__ out,
                                                  long out_size_l, int omode) {
  __shared__ float s0r[HID], s0i[HID], s1r[HID], s1i[HID];
  __shared__ float twr[HID], twi[HID];
  __shared__ float redr[256], redi[256];
  __shared__ float4 xs4[INP / 4];

  int tid = threadIdx.x;
  int b = blockIdx.x;

  init_twiddles(twr, twi, tid);
  if (tid < INP / 4) xs4[tid] = ((const float4*)(A + (size_t)b * INP))[tid];
  __syncthreads();

  float upreg[40];
#pragma unroll
  for (int se = 0; se < 40; ++se) {
    int n = ((se >> 3) << 11) + ((se & 7) << 8) + tid;
    upreg[se] = bias[n];
  }
  for (int kb = 0; kb < 4; ++kb) {
    float4 xv[8];
#pragma unroll
    for (int j = 0; j < 8; ++j) xv[j] = xs4[kb * 8 + j];
#pragma unroll
    for (int se = 0; se < 40; ++se) {
      int n = ((se >> 3) << 11) + ((se & 7) << 8) + tid;
      const float4* wr = (const float4*)(W + (size_t)n * INP + (kb << 5));
      float a = 0.f;
#pragma unroll
      for (int j = 0; j < 8; ++j) {
        float4 wv = wr[j];
        a += xv[j].x * wv.x + xv[j].y * wv.y + xv[j].z * wv.z + xv[j].w * wv.w;
      }
      upreg[se] += a;
    }
  }
#define UPR(e, s) (upreg[(s) * 8 + (e)])
#pragma unroll
  for (int e = 0; e < 8; ++e) {
    int k = tid + (e << 8);
    float u = UPR(e, 0);
    float sv = sinf(u), cv = cosf(u);
    float hr = hxr[(size_t)b * HID + k];
    float hi = hxi[(size_t)b * HID + k];
    s0r[k] = cv * hr - sv * hi;
    s0i[k] = cv * hi + sv * hr;
  }
  __syncthreads();
  ROW_PIPELINE(UPR)
#undef UPR
}

extern "C" void kernel_launch(void* const* d_in, const int* in_sizes, int n_in,
                              void* d_out, int out_size, void* d_ws, size_t ws_size,
                              hipStream_t stream) {
  const float* input   = (const float*)d_in[0];
  const float* hx_real = (const float*)d_in[1];
  const float* hx_imag = (const float*)d_in[2];
  const float* W       = (const float*)d_in[3];
  const float* bvec    = (const float*)d_in[4];
  const float* beta    = (const float*)d_in[5];
  const int*   perm    = (const int*)d_in[6];

  // Output convention dispatch (the experiment of this round):
  //   out_size == B*H      -> real part only (complex->float32 cast hypothesis)
  //   out_size == 2*B*H    -> PLANAR re-plane||im-plane (interleaved falsified in r2-r4)
  //   else                 -> interleaved fallback
  int omode;
  if (out_size == BATCH * HID) omode = 2;
  else if (out_size == 2 * BATCH * HID) omode = 1;
  else omode = 0;

  const size_t rowbytes = (size_t)FIVEH * sizeof(float);  // 40960
  long chunk = (long)(ws_size / rowbytes);
  if (chunk > BATCH) chunk = BATCH;
  chunk &= ~31L;

  if (chunk >= 32) {
    float* up = (float*)d_ws;
    for (long row0 = 0; row0 < BATCH; row0 += chunk) {
      int rows = (int)((row0 + chunk <= BATCH) ? chunk : (BATCH - row0));
      dim3 g(FIVEH / 256, rows / 32);
      gemm32<<<g, 256, 0, stream>>>(input, W, bvec, up, (int)row0, rows);
      urnn_row<<<rows, 256, 0, stream>>>(up, hx_real, hx_imag, beta, perm,
                                         (float*)d_out, (int)row0, (long)out_size, omode);
    }
  } else {
    urnn_fused<<<BATCH, 256, 0, stream>>>(input, W, bvec, hx_real, hx_imag, beta, perm,
                                          (float*)d_out, (long)out_size, omode);
  }
}

// Round 6
// 194.122 us; speedup vs baseline: 1.6157x; 1.6157x over previous
//
#include <hip/hip_runtime.h>

#define HID 2048
#define FIVEH 10240
#define INP 128
#define BATCH 2048

typedef _Float16 half8 __attribute__((ext_vector_type(8)));
typedef float f32x4 __attribute__((ext_vector_type(4)));

// load 8 consecutive f32, convert to half8 in-register
__device__ __forceinline__ half8 cvt8(const float* p) {
  float4 a = *(const float4*)p;
  float4 b = *(const float4*)(p + 4);
  half8 h;
  h[0] = (_Float16)a.x; h[1] = (_Float16)a.y; h[2] = (_Float16)a.z; h[3] = (_Float16)a.w;
  h[4] = (_Float16)b.x; h[5] = (_Float16)b.y; h[6] = (_Float16)b.z; h[7] = (_Float16)b.w;
  return h;
}

// ---------------- MFMA GEMM (exonerated in r2-r4 cross-check vs exact f32) ------------
// Wave: 4 m-tiles (64 rows) x 128-col strip, K=128 in 4 MFMA k-steps.
// B-frag reuse across 4 m-tiles cuts W re-reads 4x vs 1-tile/wave.
__global__ __launch_bounds__(256) void gemm_up(const float* __restrict__ A,
                                               const float* __restrict__ W,
                                               const float* __restrict__ bias,
                                               _Float16* __restrict__ up16,
                                               int row0, int nrows) {
  int tid = threadIdx.x, wave = tid >> 6, lane = tid & 63;
  int mg_count = nrows >> 6;
  int wid = blockIdx.x * 4 + wave;
  if (wid >= mg_count * 80) return;
  int mg = wid % mg_count;
  int ns = wid / mg_count;
  int nl = lane & 15, quad = lane >> 4;

  half8 af[4][4];
#pragma unroll
  for (int mt = 0; mt < 4; ++mt) {
    const float* arow = A + (size_t)(row0 + mg * 64 + mt * 16 + nl) * INP + quad * 8;
#pragma unroll
    for (int ks = 0; ks < 4; ++ks) af[mt][ks] = cvt8(arow + ks * 32);
  }

#pragma unroll
  for (int nt = 0; nt < 8; ++nt) {
    int ncol = ns * 128 + nt * 16 + nl;
    const float* wrow = W + (size_t)ncol * INP + quad * 8;
    half8 bf[4];
#pragma unroll
    for (int ks = 0; ks < 4; ++ks) bf[ks] = cvt8(wrow + ks * 32);
    float bv = bias[ncol];
#pragma unroll
    for (int mt = 0; mt < 4; ++mt) {
      f32x4 acc = {0.f, 0.f, 0.f, 0.f};
#pragma unroll
      for (int ks = 0; ks < 4; ++ks)
        acc = __builtin_amdgcn_mfma_f32_16x16x32_f16(af[mt][ks], bf[ks], acc, 0, 0, 0);
      int mbase = mg * 64 + mt * 16 + quad * 4;
#pragma unroll
      for (int r = 0; r < 4; ++r)
        up16[(size_t)(mbase + r) * FIVEH + ncol] = (_Float16)(acc[r] + bv);
    }
  }
}

// ---------------- row pipeline ----------------
__device__ __forceinline__ void fft_passes(float*& ar, float*& ai, float*& br, float*& bi,
                                           const float* twr, const float* twi,
                                           int tid, float sgn) {
  for (int p = 1; p < HID; p <<= 1) {
#pragma unroll
    for (int t = 0; t < 4; ++t) {
      int i = tid + (t << 8);
      int kk = i & (p - 1);
      int j = ((i - kk) << 1) + kk;
      float xr = ar[i], xi = ai[i];
      float yr = ar[i + 1024], yi = ai[i + 1024];
      float wr = twr[p + kk];
      float wi = sgn * twi[p + kk];   // table = exp(-i*pi*k/p); sgn=-1 conjugates (ifft)
      float tr = wr * yr - wi * yi;
      float ti = wr * yi + wi * yr;
      br[j] = xr + tr;
      bi[j] = xi + ti;
      br[j + p] = xr - tr;
      bi[j + p] = xi - ti;
    }
    __syncthreads();
    float* tmp;
    tmp = ar; ar = br; br = tmp;
    tmp = ai; ai = bi; bi = tmp;
  }
}

// wave shfl reduce + tiny LDS combine (2 barriers total)
__device__ __forceinline__ void block_reduce2(float& pr, float& pi,
                                              float* redr, float* redi, int tid) {
  for (int off = 32; off > 0; off >>= 1) {
    pr += __shfl_down(pr, off, 64);
    pi += __shfl_down(pi, off, 64);
  }
  if ((tid & 63) == 0) { redr[tid >> 6] = pr; redi[tid >> 6] = pi; }
  __syncthreads();
  pr = redr[0] + redr[1] + redr[2] + redr[3];
  pi = redi[0] + redi[1] + redi[2] + redi[3];
  __syncthreads();
}

__device__ __forceinline__ void init_twiddles(float* twr, float* twi, int tid) {
  for (int i = tid; i < HID; i += 256) {
    if (i > 0) {
      int p = 1 << (31 - __clz(i));
      int k = i - p;
      float ang = -3.14159265358979f * (float)k / (float)p;
      float sv, cv; __sincosf(ang, &sv, &cv);
      twr[i] = cv; twi[i] = sv;
    } else { twr[0] = 1.f; twi[0] = 0.f; }
  }
}

// omode: 0 interleaved, 1 planar (re||im — the verified convention), 2 real-only
// UP(e,s) yields up[b][s*HID + tid + e*256] as float
#define ROW_PIPELINE(UP)                                                        \
  float *car = s0r, *cai = s0i, *cbr = s1r, *cbi = s1i;                         \
  fft_passes(car, cai, cbr, cbi, twr, twi, tid, 1.0f);                          \
  float cc[8], ss[8];                                                           \
  {                                                                             \
    float pr = 0.f, pi = 0.f;                                                   \
    _Pragma("unroll") for (int e = 0; e < 8; ++e) {                             \
      int k = tid + (e << 8);                                                   \
      float sv, cv; __sincosf(UP(e, 3), &sv, &cv);                              \
      cc[e] = cv; ss[e] = sv;                                                   \
      float hr = car[k], hi = cai[k];                                           \
      pr += cv * hr + sv * hi;                                                  \
      pi += cv * hi - sv * hr;                                                  \
    }                                                                           \
    block_reduce2(pr, pi, redr, redi, tid);                                     \
    _Pragma("unroll") for (int e = 0; e < 8; ++e) {                             \
      int k = tid + (e << 8);                                                   \
      car[k] -= 2.f * (cc[e] * pr - ss[e] * pi);                                \
      cai[k] -= 2.f * (cc[e] * pi + ss[e] * pr);                                \
    }                                                                           \
  }                                                                             \
  __syncthreads();                                                              \
  _Pragma("unroll") for (int e = 0; e < 8; ++e) {                               \
    int k = tid + (e << 8);                                                     \
    float sv, cv; __sincosf(UP(e, 1), &sv, &cv);                                \
    int pk = perm[k];                                                           \
    float hr = car[pk], hi = cai[pk];                                           \
    cbr[k] = cv * hr - sv * hi;                                                 \
    cbi[k] = cv * hi + sv * hr;                                                 \
  }                                                                             \
  __syncthreads();                                                              \
  { float* t = car; car = cbr; cbr = t; t = cai; cai = cbi; cbi = t; }          \
  fft_passes(car, cai, cbr, cbi, twr, twi, tid, -1.0f);                         \
  float prj_r, prj_i;                                                           \
  {                                                                             \
    float pr = 0.f, pi = 0.f;                                                   \
    _Pragma("unroll") for (int e = 0; e < 8; ++e) {                             \
      int k = tid + (e << 8);                                                   \
      float sv, cv; __sincosf(UP(e, 4), &sv, &cv);                              \
      cc[e] = cv; ss[e] = sv;                                                   \
      float hr = car[k], hi = cai[k];                                           \
      pr += cv * hr + sv * hi;                                                  \
      pi += cv * hi - sv * hr;                                                  \
    }                                                                           \
    block_reduce2(pr, pi, redr, redi, tid);                                     \
    prj_r = pr; prj_i = pi;                                                     \
  }                                                                             \
  const float invN = 1.0f / (float)HID;                                         \
  _Pragma("unroll") for (int e = 0; e < 8; ++e) {                               \
    int k = tid + (e << 8);                                                     \
    float hr = car[k] - 2.f * (cc[e] * prj_r - ss[e] * prj_i);                  \
    float hi = cai[k] - 2.f * (cc[e] * prj_i + ss[e] * prj_r);                  \
    float s3, c3; __sincosf(UP(e, 2), &s3, &c3);                                \
    float zr = (c3 * hr - s3 * hi) * invN;                                      \
    float zi = (c3 * hi + s3 * hr) * invN;                                      \
    float mag = sqrtf(zr * zr + zi * zi);                                       \
    float nm = mag + beta[k];                                                   \
    nm = nm > 0.f ? nm : 0.f;                                                   \
    float orr, oii;                                                             \
    if (mag > 0.f) { float sc = nm / mag; orr = zr * sc; oii = zi * sc; }       \
    else { orr = nm; oii = 0.f; }                                               \
    long m = (long)b * HID + k;                                                 \
    if (omode == 0) {                                                           \
      if (2 * m + 1 < out_size_l) {                                             \
        float2 o; o.x = orr; o.y = oii;                                         \
        *(float2*)(out + 2 * m) = o;                                            \
      }                                                                         \
    } else if (omode == 1) {                                                    \
      const long half = (long)BATCH * HID;                                      \
      if (half + m < out_size_l) { out[m] = orr; out[half + m] = oii; }         \
    } else {                                                                    \
      if (m < out_size_l) out[m] = orr;                                         \
    }                                                                           \
  }

// ---------------- chunked-path row kernel: reads staged f16 up ----------------
__global__ __launch_bounds__(256) void urnn_row(const _Float16* __restrict__ up16,
                                                const float* __restrict__ hxr,
                                                const float* __restrict__ hxi,
                                                const float* __restrict__ beta,
                                                const int* __restrict__ perm,
                                                float* __restrict__ out,
                                                int row0, long out_size_l, int omode) {
  __shared__ float s0r[HID], s0i[HID], s1r[HID], s1i[HID];
  __shared__ float twr[HID], twi[HID];
  __shared__ float redr[4], redi[4];

  int tid = threadIdx.x;
  int b = row0 + blockIdx.x;
  const _Float16* uprow = up16 + (size_t)blockIdx.x * FIVEH;
#define UPG(e, s) ((float)uprow[(s) * HID + tid + ((e) << 8)])

  init_twiddles(twr, twi, tid);
#pragma unroll
  for (int e = 0; e < 8; ++e) {
    int k = tid + (e << 8);
    float sv, cv; __sincosf(UPG(e, 0), &sv, &cv);
    float hr = hxr[(size_t)b * HID + k];
    float hi = hxi[(size_t)b * HID + k];
    s0r[k] = cv * hr - sv * hi;
    s0i[k] = cv * hi + sv * hr;
  }
  __syncthreads();
  ROW_PIPELINE(UPG)
#undef UPG
}

// ---------------- ws-free fused fallback (f32-exact per-thread GEMM) ------------------
__global__ __launch_bounds__(256) void urnn_fused(const float* __restrict__ A,
                                                  const float* __restrict__ W,
                                                  const float* __restrict__ bias,
                                                  const float* __restrict__ hxr,
                                                  const float* __restrict__ hxi,
                                                  const float* __restrict__ beta,
                                                  const int* __restrict__ perm,
                                                  float* __restrict__ out,
                                                  long out_size_l, int omode) {
  __shared__ float s0r[HID], s0i[HID], s1r[HID], s1i[HID];
  __shared__ float twr[HID], twi[HID];
  __shared__ float redr[4], redi[4];
  __shared__ float4 xs4[INP / 4];

  int tid = threadIdx.x;
  int b = blockIdx.x;

  init_twiddles(twr, twi, tid);
  if (tid < INP / 4) xs4[tid] = ((const float4*)(A + (size_t)b * INP))[tid];
  __syncthreads();

  float upreg[40];
#pragma unroll
  for (int se = 0; se < 40; ++se) {
    int n = ((se >> 3) << 11) + ((se & 7) << 8) + tid;
    upreg[se] = bias[n];
  }
  for (int kb = 0; kb < 4; ++kb) {
    float4 xv[8];
#pragma unroll
    for (int j = 0; j < 8; ++j) xv[j] = xs4[kb * 8 + j];
#pragma unroll
    for (int se = 0; se < 40; ++se) {
      int n = ((se >> 3) << 11) + ((se & 7) << 8) + tid;
      const float4* wr = (const float4*)(W + (size_t)n * INP + (kb << 5));
      float a = 0.f;
#pragma unroll
      for (int j = 0; j < 8; ++j) {
        float4 wv = wr[j];
        a += xv[j].x * wv.x + xv[j].y * wv.y + xv[j].z * wv.z + xv[j].w * wv.w;
      }
      upreg[se] += a;
    }
  }
#define UPR(e, s) (upreg[(s) * 8 + (e)])
#pragma unroll
  for (int e = 0; e < 8; ++e) {
    int k = tid + (e << 8);
    float sv, cv; __sincosf(UPR(e, 0), &sv, &cv);
    float hr = hxr[(size_t)b * HID + k];
    float hi = hxi[(size_t)b * HID + k];
    s0r[k] = cv * hr - sv * hi;
    s0i[k] = cv * hi + sv * hr;
  }
  __syncthreads();
  ROW_PIPELINE(UPR)
#undef UPR
}

extern "C" void kernel_launch(void* const* d_in, const int* in_sizes, int n_in,
                              void* d_out, int out_size, void* d_ws, size_t ws_size,
                              hipStream_t stream) {
  const float* input   = (const float*)d_in[0];
  const float* hx_real = (const float*)d_in[1];
  const float* hx_imag = (const float*)d_in[2];
  const float* W       = (const float*)d_in[3];
  const float* bvec    = (const float*)d_in[4];
  const float* beta    = (const float*)d_in[5];
  const int*   perm    = (const int*)d_in[6];

  // verified in r5: planar for out_size == 2*B*H
  int omode;
  if (out_size == BATCH * HID) omode = 2;
  else if (out_size == 2 * BATCH * HID) omode = 1;
  else omode = 0;

  // f16 up staging: 20480 B/row -> full batch needs 41.94 MB (ws measured >= that in r5)
  const size_t rowbytes = (size_t)FIVEH * sizeof(_Float16);
  long chunk = (long)(ws_size / rowbytes);
  if (chunk > BATCH) chunk = BATCH;
  chunk &= ~63L;                 // gemm_up works in 64-row groups

  if (chunk >= 64) {
    _Float16* up16 = (_Float16*)d_ws;
    for (long row0 = 0; row0 < BATCH; row0 += chunk) {
      int rows = (int)((row0 + chunk <= BATCH) ? chunk : (BATCH - row0));
      int waves = (rows >> 6) * 80;
      gemm_up<<<(waves + 3) / 4, 256, 0, stream>>>(input, W, bvec, up16, (int)row0, rows);
      urnn_row<<<rows, 256, 0, stream>>>(up16, hx_real, hx_imag, beta, perm,
                                         (float*)d_out, (int)row0, (long)out_size, omode);
    }
  } else {
    urnn_fused<<<BATCH, 256, 0, stream>>>(input, W, bvec, hx_real, hx_imag, beta, perm,
                                          (float*)d_out, (long)out_size, omode);
  }
}

// Round 7
// 155.069 us; speedup vs baseline: 2.0226x; 1.2518x over previous
//
#include <hip/hip_runtime.h>

#define HID 2048
#define FIVEH 10240
#define INP 128
#define BATCH 2048

typedef _Float16 half8 __attribute__((ext_vector_type(8)));
typedef float f32x4 __attribute__((ext_vector_type(4)));

// ---------------- f32 -> f16 bulk convert (8 elems/thread) ----------------
__global__ __launch_bounds__(256) void convert_f16(const float* __restrict__ src,
                                                   _Float16* __restrict__ dst) {
  int idx = (blockIdx.x * 256 + threadIdx.x) * 8;
  float4 a = *(const float4*)(src + idx);
  float4 b = *(const float4*)(src + idx + 4);
  half8 h;
  h[0] = (_Float16)a.x; h[1] = (_Float16)a.y; h[2] = (_Float16)a.z; h[3] = (_Float16)a.w;
  h[4] = (_Float16)b.x; h[5] = (_Float16)b.y; h[6] = (_Float16)b.z; h[7] = (_Float16)b.w;
  *(half8*)(dst + idx) = h;
}

// ---------------- MFMA GEMM, f16 operands preconverted ----------------
// Wave: 4 m-tiles (64 rows) x 128-col strip, K=128 in 4 MFMA k-steps.
__global__ __launch_bounds__(256) void gemm_up(const _Float16* __restrict__ Ah,
                                               const _Float16* __restrict__ Wh,
                                               const float* __restrict__ bias,
                                               _Float16* __restrict__ up16,
                                               int row0, int nrows) {
  int tid = threadIdx.x, wave = tid >> 6, lane = tid & 63;
  int mg_count = nrows >> 6;
  int wid = blockIdx.x * 4 + wave;
  if (wid >= mg_count * 80) return;
  int mg = wid % mg_count;
  int ns = wid / mg_count;
  int nl = lane & 15, quad = lane >> 4;

  half8 af[4][4];
#pragma unroll
  for (int mt = 0; mt < 4; ++mt) {
    const _Float16* arow = Ah + (size_t)(row0 + mg * 64 + mt * 16 + nl) * INP + quad * 8;
#pragma unroll
    for (int ks = 0; ks < 4; ++ks) af[mt][ks] = *(const half8*)(arow + ks * 32);
  }

#pragma unroll
  for (int nt = 0; nt < 8; ++nt) {
    int ncol = ns * 128 + nt * 16 + nl;
    const _Float16* wrow = Wh + (size_t)ncol * INP + quad * 8;
    half8 bf[4];
#pragma unroll
    for (int ks = 0; ks < 4; ++ks) bf[ks] = *(const half8*)(wrow + ks * 32);
    float bv = bias[ncol];
#pragma unroll
    for (int mt = 0; mt < 4; ++mt) {
      f32x4 acc = {0.f, 0.f, 0.f, 0.f};
#pragma unroll
      for (int ks = 0; ks < 4; ++ks)
        acc = __builtin_amdgcn_mfma_f32_16x16x32_f16(af[mt][ks], bf[ks], acc, 0, 0, 0);
      int mbase = mg * 64 + mt * 16 + quad * 4;
#pragma unroll
      for (int r = 0; r < 4; ++r)
        up16[(size_t)(mbase + r) * FIVEH + ncol] = (_Float16)(acc[r] + bv);
    }
  }
}

// ---------------- radix-4 Stockham FFT (float2, on-the-fly twiddles) ----------------
// N=2048 = 2 * 4^5. Pass sequence: radix-2 (L=1, twiddle-free) then radix-4 with
// L = 2,8,32,128,512. Stockham autosort: natural order in AND out.
// Verified by hand at N=8: r2 then r4(L=2) reproduces numpy DFT exactly.
// sgn = -1 forward, +1 inverse (unscaled).
__device__ __forceinline__ void fft_r4(float2*& src, float2*& dst, int tid, float sgn) {
  // radix-2 pass, L=1: dst[2i]=a+b, dst[2i+1]=a-b  (b128 store: 2i,2i+1 contiguous)
#pragma unroll
  for (int t = 0; t < 4; ++t) {
    int i = tid + (t << 8);
    float2 a = src[i], b = src[i + 1024];
    float4 o;
    o.x = a.x + b.x; o.y = a.y + b.y;
    o.z = a.x - b.x; o.w = a.y - b.y;
    *(float4*)&dst[2 * i] = o;
  }
  __syncthreads();
  { float2* t = src; src = dst; dst = t; }

#pragma unroll
  for (int pass = 0; pass < 5; ++pass) {
    const int L = 2 << (2 * pass);            // 2,8,32,128,512
    const float co = sgn * 1.5707963267948966f / (float)L;   // sgn*pi/(2L)
#pragma unroll
    for (int t = 0; t < 2; ++t) {
      int i = tid + (t << 8);
      int k = i & (L - 1);
      int base4 = ((i - k) << 2) + k;         // 4*m*L + k
      float2 x0 = src[i], x1 = src[i + 512], x2 = src[i + 1024], x3 = src[i + 1536];
      float ang = co * (float)k;              // w_j = cis(j*ang)
      float s1, c1; __sincosf(ang, &s1, &c1);
      float c2 = c1 * c1 - s1 * s1, s2 = 2.f * c1 * s1;
      float c3 = c1 * c2 - s1 * s2, s3 = c1 * s2 + s1 * c2;
      float y1r = x1.x * c1 - x1.y * s1, y1i = x1.x * s1 + x1.y * c1;
      float y2r = x2.x * c2 - x2.y * s2, y2i = x2.x * s2 + x2.y * c2;
      float y3r = x3.x * c3 - x3.y * s3, y3i = x3.x * s3 + x3.y * c3;
      float t0r = x0.x + y2r, t0i = x0.y + y2i;
      float t1r = x0.x - y2r, t1i = x0.y - y2i;
      float t2r = y1r + y3r, t2i = y1i + y3i;
      float t3r = y1r - y3r, t3i = y1i - y3i;
      dst[base4]         = make_float2(t0r + t2r, t0i + t2i);
      dst[base4 + 2 * L] = make_float2(t0r - t2r, t0i - t2i);
      // z1 = t1 + sgn*i*t3 ; z3 = t1 - sgn*i*t3
      dst[base4 + L]     = make_float2(t1r - sgn * t3i, t1i + sgn * t3r);
      dst[base4 + 3 * L] = make_float2(t1r + sgn * t3i, t1i - sgn * t3r);
    }
    __syncthreads();
    { float2* t = src; src = dst; dst = t; }
  }
}
// 6 swaps total -> result lands back in the buffer fft_r4 was given as src.

// wave shfl reduce + tiny LDS combine
__device__ __forceinline__ void block_reduce2(float& pr, float& pi,
                                              float* redr, float* redi, int tid) {
  for (int off = 32; off > 0; off >>= 1) {
    pr += __shfl_down(pr, off, 64);
    pi += __shfl_down(pi, off, 64);
  }
  if ((tid & 63) == 0) { redr[tid >> 6] = pr; redi[tid >> 6] = pi; }
  __syncthreads();
  pr = redr[0] + redr[1] + redr[2] + redr[3];
  pi = redi[0] + redi[1] + redi[2] + redi[3];
  __syncthreads();
}

// omode: 0 interleaved, 1 planar (re||im — verified r5), 2 real-only
// UP(e,s) yields up[b][s*HID + tid + e*256] as float
#define ROW_PIPELINE(UP)                                                        \
  float2 *ca = sA, *cb = sB;                                                    \
  fft_r4(ca, cb, tid, -1.0f);                                                   \
  float cc[8], ss[8];                                                           \
  {                                                                             \
    float pr = 0.f, pi = 0.f;                                                   \
    _Pragma("unroll") for (int e = 0; e < 8; ++e) {                             \
      int k = tid + (e << 8);                                                   \
      float sv, cv; __sincosf(UP(e, 3), &sv, &cv);                              \
      cc[e] = cv; ss[e] = sv;                                                   \
      float2 h = ca[k];                                                         \
      pr += cv * h.x + sv * h.y;                                                \
      pi += cv * h.y - sv * h.x;                                                \
    }                                                                           \
    block_reduce2(pr, pi, redr, redi, tid);                                     \
    _Pragma("unroll") for (int e = 0; e < 8; ++e) {                             \
      int k = tid + (e << 8);                                                   \
      float2 h = ca[k];                                                         \
      h.x -= 2.f * (cc[e] * pr - ss[e] * pi);                                   \
      h.y -= 2.f * (cc[e] * pi + ss[e] * pr);                                   \
      ca[k] = h;                                                                \
    }                                                                           \
  }                                                                             \
  __syncthreads();                                                              \
  _Pragma("unroll") for (int e = 0; e < 8; ++e) {                               \
    int k = tid + (e << 8);                                                     \
    float sv, cv; __sincosf(UP(e, 1), &sv, &cv);                                \
    float2 h = ca[perm[k]];                                                     \
    cb[k] = make_float2(cv * h.x - sv * h.y, cv * h.y + sv * h.x);              \
  }                                                                             \
  __syncthreads();                                                              \
  { float2* t = ca; ca = cb; cb = t; }                                          \
  fft_r4(ca, cb, tid, 1.0f);                                                    \
  float prj_r, prj_i;                                                           \
  {                                                                             \
    float pr = 0.f, pi = 0.f;                                                   \
    _Pragma("unroll") for (int e = 0; e < 8; ++e) {                             \
      int k = tid + (e << 8);                                                   \
      float sv, cv; __sincosf(UP(e, 4), &sv, &cv);                              \
      cc[e] = cv; ss[e] = sv;                                                   \
      float2 h = ca[k];                                                         \
      pr += cv * h.x + sv * h.y;                                                \
      pi += cv * h.y - sv * h.x;                                                \
    }                                                                           \
    block_reduce2(pr, pi, redr, redi, tid);                                     \
    prj_r = pr; prj_i = pi;                                                     \
  }                                                                             \
  const float invN = 1.0f / (float)HID;                                         \
  _Pragma("unroll") for (int e = 0; e < 8; ++e) {                               \
    int k = tid + (e << 8);                                                     \
    float2 h = ca[k];                                                           \
    float hr = h.x - 2.f * (cc[e] * prj_r - ss[e] * prj_i);                     \
    float hi = h.y - 2.f * (cc[e] * prj_i + ss[e] * prj_r);                     \
    float s3, c3; __sincosf(UP(e, 2), &s3, &c3);                                \
    float zr = (c3 * hr - s3 * hi) * invN;                                      \
    float zi = (c3 * hi + s3 * hr) * invN;                                      \
    float mag = sqrtf(zr * zr + zi * zi);                                       \
    float nm = mag + beta[k];                                                   \
    nm = nm > 0.f ? nm : 0.f;                                                   \
    float orr, oii;                                                             \
    if (mag > 0.f) { float sc = nm / mag; orr = zr * sc; oii = zi * sc; }       \
    else { orr = nm; oii = 0.f; }                                               \
    long m = (long)b * HID + k;                                                 \
    if (omode == 1) {                                                           \
      const long half = (long)BATCH * HID;                                      \
      if (half + m < out_size_l) { out[m] = orr; out[half + m] = oii; }         \
    } else if (omode == 0) {                                                    \
      if (2 * m + 1 < out_size_l) {                                             \
        float2 o; o.x = orr; o.y = oii;                                         \
        *(float2*)(out + 2 * m) = o;                                            \
      }                                                                         \
    } else {                                                                    \
      if (m < out_size_l) out[m] = orr;                                         \
    }                                                                           \
  }

// ---------------- chunked-path row kernel: reads staged f16 up ----------------
__global__ __launch_bounds__(256) void urnn_row(const _Float16* __restrict__ up16,
                                                const float* __restrict__ hxr,
                                                const float* __restrict__ hxi,
                                                const float* __restrict__ beta,
                                                const int* __restrict__ perm,
                                                float* __restrict__ out,
                                                int row0, long out_size_l, int omode) {
  __shared__ float2 sA[HID], sB[HID];
  __shared__ float redr[4], redi[4];

  int tid = threadIdx.x;
  int b = row0 + blockIdx.x;
  const _Float16* uprow = up16 + (size_t)blockIdx.x * FIVEH;
#define UPG(e, s) ((float)uprow[(s) * HID + tid + ((e) << 8)])

#pragma unroll
  for (int e = 0; e < 8; ++e) {
    int k = tid + (e << 8);
    float sv, cv; __sincosf(UPG(e, 0), &sv, &cv);
    float hr = hxr[(size_t)b * HID + k];
    float hi = hxi[(size_t)b * HID + k];
    sA[k] = make_float2(cv * hr - sv * hi, cv * hi + sv * hr);
  }
  __syncthreads();
  ROW_PIPELINE(UPG)
#undef UPG
}

// ---------------- ws-free fused fallback (f32-exact per-thread GEMM) ------------------
__global__ __launch_bounds__(256) void urnn_fused(const float* __restrict__ A,
                                                  const float* __restrict__ W,
                                                  const float* __restrict__ bias,
                                                  const float* __restrict__ hxr,
                                                  const float* __restrict__ hxi,
                                                  const float* __restrict__ beta,
                                                  const int* __restrict__ perm,
                                                  float* __restrict__ out,
                                                  long out_size_l, int omode) {
  __shared__ float2 sA[HID], sB[HID];
  __shared__ float redr[4], redi[4];
  __shared__ float4 xs4[INP / 4];

  int tid = threadIdx.x;
  int b = blockIdx.x;

  if (tid < INP / 4) xs4[tid] = ((const float4*)(A + (size_t)b * INP))[tid];
  __syncthreads();

  float upreg[40];
#pragma unroll
  for (int se = 0; se < 40; ++se) {
    int n = ((se >> 3) << 11) + ((se & 7) << 8) + tid;
    upreg[se] = bias[n];
  }
  for (int kb = 0; kb < 4; ++kb) {
    float4 xv[8];
#pragma unroll
    for (int j = 0; j < 8; ++j) xv[j] = xs4[kb * 8 + j];
#pragma unroll
    for (int se = 0; se < 40; ++se) {
      int n = ((se >> 3) << 11) + ((se & 7) << 8) + tid;
      const float4* wr = (const float4*)(W + (size_t)n * INP + (kb << 5));
      float a = 0.f;
#pragma unroll
      for (int j = 0; j < 8; ++j) {
        float4 wv = wr[j];
        a += xv[j].x * wv.x + xv[j].y * wv.y + xv[j].z * wv.z + xv[j].w * wv.w;
      }
      upreg[se] += a;
    }
  }
#define UPR(e, s) (upreg[(s) * 8 + (e)])
#pragma unroll
  for (int e = 0; e < 8; ++e) {
    int k = tid + (e << 8);
    float sv, cv; __sincosf(UPR(e, 0), &sv, &cv);
    float hr = hxr[(size_t)b * HID + k];
    float hi = hxi[(size_t)b * HID + k];
    sA[k] = make_float2(cv * hr - sv * hi, cv * hi + sv * hr);
  }
  __syncthreads();
  ROW_PIPELINE(UPR)
#undef UPR
}

extern "C" void kernel_launch(void* const* d_in, const int* in_sizes, int n_in,
                              void* d_out, int out_size, void* d_ws, size_t ws_size,
                              hipStream_t stream) {
  const float* input   = (const float*)d_in[0];
  const float* hx_real = (const float*)d_in[1];
  const float* hx_imag = (const float*)d_in[2];
  const float* W       = (const float*)d_in[3];
  const float* bvec    = (const float*)d_in[4];
  const float* beta    = (const float*)d_in[5];
  const int*   perm    = (const int*)d_in[6];

  // verified in r5: planar for out_size == 2*B*H
  int omode;
  if (out_size == BATCH * HID) omode = 2;
  else if (out_size == 2 * BATCH * HID) omode = 1;
  else omode = 0;

  // ws layout: Ah (0.5MB) | Wh (2.62MB) | up16 chunk (20480 B/row)
  const size_t na = (size_t)BATCH * INP;     // 262144
  const size_t nw = (size_t)FIVEH * INP;     // 1310720
  const size_t fixed = (na + nw) * sizeof(_Float16);   // 3.1MB, 16B-aligned
  const size_t rowbytes = (size_t)FIVEH * sizeof(_Float16);
  long chunk = (ws_size > fixed) ? (long)((ws_size - fixed) / rowbytes) : 0;
  if (chunk > BATCH) chunk = BATCH;
  chunk &= ~63L;                 // gemm_up works in 64-row groups

  if (chunk >= 64) {
    _Float16* Ah = (_Float16*)d_ws;
    _Float16* Wh = Ah + na;
    _Float16* up16 = (_Float16*)((char*)d_ws + fixed);
    convert_f16<<<(int)(na / 2048), 256, 0, stream>>>(input, Ah);
    convert_f16<<<(int)(nw / 2048), 256, 0, stream>>>(W, Wh);
    for (long row0 = 0; row0 < BATCH; row0 += chunk) {
      int rows = (int)((row0 + chunk <= BATCH) ? chunk : (BATCH - row0));
      int waves = (rows >> 6) * 80;
      gemm_up<<<(waves + 3) / 4, 256, 0, stream>>>(Ah, Wh, bvec, up16, (int)row0, rows);
      urnn_row<<<rows, 256, 0, stream>>>(up16, hx_real, hx_imag, beta, perm,
                                         (float*)d_out, (int)row0, (long)out_size, omode);
    }
  } else {
    urnn_fused<<<BATCH, 256, 0, stream>>>(input, W, bvec, hx_real, hx_imag, beta, perm,
                                          (float*)d_out, (long)out_size, omode);
  }
}